// Round 1
// 2185.983 us; speedup vs baseline: 1.0059x; 1.0059x over previous
//
#include <hip/hip_runtime.h>
#include <hip/hip_bf16.h>
#include <math.h>
#include <stdint.h>

using bf16 = __hip_bfloat16;
typedef __attribute__((ext_vector_type(8))) short short8;   // 8 bf16 (MFMA A/B frag)
typedef __attribute__((ext_vector_type(4))) float floatx4;  // MFMA C/D frag (f32)
typedef __attribute__((ext_vector_type(4))) int int4v;      // i8 K=64 frag / i32 acc

typedef const __attribute__((address_space(1))) void* gptr_t;
typedef __attribute__((address_space(3))) void* lptr_t;

__device__ __forceinline__ void load_lds16(const void* g, void* l) {
    __builtin_amdgcn_global_load_lds((gptr_t)(uintptr_t)g, (lptr_t)(uintptr_t)l, 16, 0, 0);
}

// wait until at most N vector-memory ops outstanding. gfx9 vmcnt 6 bits:
// lo[3:0]=bits3:0, hi[5:4]=bits15:14; lgkm/exp left at max (no wait).
#define WAIT_VM(n) __builtin_amdgcn_s_waitcnt(0x0F70 | ((n) & 15) | (((n) >> 4) << 14))

// tanh(x) = 1 - 2/(exp(2x)+1)
__device__ __forceinline__ float fast_tanh(float x) {
    float e = __expf(2.f * x);
    return 1.f - 2.f / (e + 1.f);
}

// ---------------------------------------------------------------------------
// L1: C = tanh(A·W^T + b), bf16 core (r7 structure: 128x128, 4 waves, wave
// tile 64x64, dbuf 64 KB, 2 blocks/CU, fine WAIT_VM, XCD swizzle).
// Output written as i8 (x1*127) — consumed by the i8 L2. tanh out in (-1,1):
// linear i8 gives delta_x RMS ~0.0023, 8x better than e4m3's ~0.018 (the
// r8 near-miss: absmax 0.195 vs 0.152 was pure e4m3 mantissa noise; the
// MX fragment layout itself was correct).
// ---------------------------------------------------------------------------
__global__ void __launch_bounds__(256, 2)
gemm_tanh4(const bf16* __restrict__ A, const bf16* __restrict__ W,
           const float* __restrict__ bias, int8_t* __restrict__ out,
           int K, int N) {
    constexpr int BM = 128, BN = 128, MT = 4, NT = 4;
    __shared__ alignas(16) bf16 lA[2][BM * 64];
    __shared__ alignas(16) bf16 lB[2][BN * 64];

    const int b   = blockIdx.x + gridDim.x * blockIdx.y;   // grid (8, 64)
    const int xcd = b & 7, j = b >> 3;
    const int bx  = j & 7;
    const int by  = xcd + 8 * (j >> 3);

    const int tid  = threadIdx.x;
    const int lane = tid & 63;
    const int w    = tid >> 6;
    const int wr   = w >> 1, wc = w & 1;
    const int quad = lane >> 4, l16 = lane & 15;
    const int brow = by * BM;
    const int bcol = bx * BN;

    const bf16* gA[4]; const bf16* gW[4]; int lq[4];
#pragma unroll
    for (int jj = 0; jj < 4; ++jj) {
        const int q = tid + jj * 256;
        const int r = q >> 3, s = (q & 7) ^ (r & 7);
        gA[jj] = A + (size_t)(brow + r) * K + s * 8;
        gW[jj] = W + (size_t)(bcol + r) * K + s * 8;
        lq[jj] = q * 8;
    }

    floatx4 acc[MT][NT];
    const floatx4 zero = {0.f, 0.f, 0.f, 0.f};
#pragma unroll
    for (int mt = 0; mt < MT; ++mt)
#pragma unroll
        for (int nt = 0; nt < NT; ++nt) acc[mt][nt] = zero;

    const int arow0 = wr * 64 + l16;
    const int brow0 = wc * 64 + l16;
    const int x7 = l16 & 7;

    const int nIter = K / 64;
#pragma unroll
    for (int jj = 0; jj < 4; ++jj) load_lds16(gA[jj], &lA[0][0] + lq[jj]);
#pragma unroll
    for (int jj = 0; jj < 4; ++jj) load_lds16(gW[jj], &lB[0][0] + lq[jj]);

    for (int kt = 0; kt < nIter; ++kt) {
        const int cur = kt & 1;
        if (kt + 1 < nIter) {
#pragma unroll
            for (int jj = 0; jj < 4; ++jj)
                load_lds16(gA[jj] + (kt + 1) * 64, &lA[cur ^ 1][0] + lq[jj]);
#pragma unroll
            for (int jj = 0; jj < 4; ++jj)
                load_lds16(gW[jj] + (kt + 1) * 64, &lB[cur ^ 1][0] + lq[jj]);
            WAIT_VM(8);
        } else {
            WAIT_VM(0);
        }
        __builtin_amdgcn_s_barrier();

#pragma unroll
        for (int kk = 0; kk < 2; ++kk) {
            const int sw = ((kk * 4 + quad) ^ x7) * 8;
            short8 af[MT], bfr[NT];
#pragma unroll
            for (int mt = 0; mt < MT; ++mt)
                af[mt] = *(const short8*)(&lA[cur][0] + (arow0 + mt * 16) * 64 + sw);
#pragma unroll
            for (int nt = 0; nt < NT; ++nt)
                bfr[nt] = *(const short8*)(&lB[cur][0] + (brow0 + nt * 16) * 64 + sw);
#pragma unroll
            for (int mt = 0; mt < MT; ++mt)
#pragma unroll
                for (int nt = 0; nt < NT; ++nt)
                    acc[mt][nt] = __builtin_amdgcn_mfma_f32_16x16x32_bf16(
                        af[mt], bfr[nt], acc[mt][nt], 0, 0, 0);
        }
        __builtin_amdgcn_s_barrier();
    }

    const int m0 = brow + wr * 64 + quad * 4;
    const int n0 = bcol + wc * 64 + l16;
#pragma unroll
    for (int mt = 0; mt < MT; ++mt)
#pragma unroll
        for (int nt = 0; nt < NT; ++nt) {
            const int n = n0 + nt * 16;
            const float bb = bias[n];
#pragma unroll
            for (int i = 0; i < 4; ++i) {
                const int m = m0 + mt * 16 + i;
                const float t = fast_tanh(acc[mt][nt][i] + bb);
                out[(size_t)m * N + n] = (int8_t)__float2int_rn(t * 127.f);
            }
        }
}

// ---------------------------------------------------------------------------
// L2: C = tanh(acc*dq[n] + b2), i8 core. A = x1*127 (i8), W = per-row-scaled
// i8 W2 (row n scaled by 127/rowmax_n), dq[n] = rowmax_n/127^2 dequant.
// mfma_i32_16x16x64_i8: frag = 16 contiguous k-bytes/lane (quad-strided) —
// byte-identical to the low/high half of r8's verified fp8 K=128 frag, so
// the staging layout is reused unchanged: 128-B rows, XOR-8 swizzle on 16-B
// chunks (slot p of row r holds chunk p^(r&7)); per kk, slot formula matches
// the bf16 kernel's free-2-way pattern. Per-CU per k128 vs bf16: LDS reads
// halved (16 vs 32 b128/wave), MFMA cyc ~halved (2x16 i8 MFMA @ ~4.6 cyc vs
// 4x16 bf16 @ ~4.85). dbuf 2 x (16+16) KB = 64 KB, 2 blk/CU, XCD swizzle.
// ---------------------------------------------------------------------------
__global__ void __launch_bounds__(256, 2)
gemm_tanh_i8(const int8_t* __restrict__ A, const int8_t* __restrict__ W,
             const float* __restrict__ dq, const float* __restrict__ bias,
             bf16* __restrict__ out, int K, int N) {
    constexpr int BM = 128, BN = 128, MT = 4, NT = 4;
    __shared__ alignas(16) int8_t lA[2][BM * 128];   // 2 x 16 KB
    __shared__ alignas(16) int8_t lB[2][BN * 128];   // 2 x 16 KB

    const int b   = blockIdx.x + gridDim.x * blockIdx.y;   // grid (8, 64)
    const int xcd = b & 7, j = b >> 3;
    const int bx  = j & 7;
    const int by  = xcd + 8 * (j >> 3);

    const int tid  = threadIdx.x;
    const int lane = tid & 63;
    const int w    = tid >> 6;
    const int wr   = w >> 1, wc = w & 1;
    const int quad = lane >> 4, l16 = lane & 15;
    const int brow = by * BM;
    const int bcol = bx * BN;

    // staging: per tile 128 rows x 8 chunks of 16 B per matrix; 4+4 /thread
    const int8_t* gA[4]; const int8_t* gW[4]; int lq[4];
#pragma unroll
    for (int jj = 0; jj < 4; ++jj) {
        const int q = tid + jj * 256;
        const int r = q >> 3, s = (q & 7) ^ (r & 7);
        gA[jj] = A + (size_t)(brow + r) * K + s * 16;
        gW[jj] = W + (size_t)(bcol + r) * K + s * 16;
        lq[jj] = q * 16;
    }

    int4v acc[MT][NT];
    const int4v izero = {0, 0, 0, 0};
#pragma unroll
    for (int mt = 0; mt < MT; ++mt)
#pragma unroll
        for (int nt = 0; nt < NT; ++nt) acc[mt][nt] = izero;

    const int arow0 = wr * 64 + l16;
    const int brow0 = wc * 64 + l16;
    const int x7 = l16 & 7;

    const int nIter = K / 128;   // 8 for K=1024
#pragma unroll
    for (int jj = 0; jj < 4; ++jj) load_lds16(gA[jj], &lA[0][0] + lq[jj]);
#pragma unroll
    for (int jj = 0; jj < 4; ++jj) load_lds16(gW[jj], &lB[0][0] + lq[jj]);

    for (int kt = 0; kt < nIter; ++kt) {
        const int cur = kt & 1;
        if (kt + 1 < nIter) {
#pragma unroll
            for (int jj = 0; jj < 4; ++jj)
                load_lds16(gA[jj] + (kt + 1) * 128, &lA[cur ^ 1][0] + lq[jj]);
#pragma unroll
            for (int jj = 0; jj < 4; ++jj)
                load_lds16(gW[jj] + (kt + 1) * 128, &lB[cur ^ 1][0] + lq[jj]);
            WAIT_VM(8);
        } else {
            WAIT_VM(0);
        }
        __builtin_amdgcn_s_barrier();

        // two K=64 MFMA groups per staged k128
#pragma unroll
        for (int kk = 0; kk < 2; ++kk) {
            const int sw = ((kk * 4 + quad) ^ x7) * 16;
            int4v af[MT], bfr[NT];
#pragma unroll
            for (int mt = 0; mt < MT; ++mt)
                af[mt] = *(const int4v*)(&lA[cur][(arow0 + mt * 16) * 128 + sw]);
#pragma unroll
            for (int nt = 0; nt < NT; ++nt)
                bfr[nt] = *(const int4v*)(&lB[cur][(brow0 + nt * 16) * 128 + sw]);
#pragma unroll
            for (int mt = 0; mt < MT; ++mt)
#pragma unroll
                for (int nt = 0; nt < NT; ++nt)
                    acc[mt][nt] = __builtin_amdgcn_mfma_i32_16x16x64_i8(
                        af[mt], bfr[nt], acc[mt][nt], 0, 0, 0);
        }
        __builtin_amdgcn_s_barrier();
    }

    const int m0 = brow + wr * 64 + quad * 4;
    const int n0 = bcol + wc * 64 + l16;
#pragma unroll
    for (int mt = 0; mt < MT; ++mt)
#pragma unroll
        for (int nt = 0; nt < NT; ++nt) {
            const int n = n0 + nt * 16;
            const float bb = bias[n];
            const float dqn = dq[n];
#pragma unroll
            for (int i = 0; i < 4; ++i) {
                const int m = m0 + mt * 16 + i;
                out[(size_t)m * N + n] =
                    __float2bfloat16(fast_tanh((float)acc[mt][nt][i] * dqn + bb));
            }
        }
}

// ---------------------------------------------------------------------------
// L3 GEMM (M=8192, N=512, K=1024) with fused RK4 logic — now on the same
// dbuf + fine-WAIT_VM structure as gemm_tanh4. 128x64 tile (BN=64 keeps the
// grid at 512 blocks = 2/CU, preserving inter-block overlap; BN=128 would
// give 256 blocks = 1/CU and lose the m114-style wave overlap that hides
// the barrier drain). 4 waves, wave tile 64x32 (MT=4, NT=2). LDS: dbuf
// 2*(16+8) KB = 48 KB -> 2 blocks/CU = 96 KB. Staging: 4 A + 2 B chunks of
// 16 B per thread, XOR-8 swizzle (slot p of row r holds k-chunk p^(r&7)).
// K-summation order per output element is IDENTICAL to the old 64x64 core
// (same kt/kk/MFMA-K=32 sequence) -> bit-identical results.
// kv = acc + b3[n].
// mode 0 (k1):   kacc = kv;     x0 = bf16(hb + alpha*kv + te)
// mode 1 (k2/3): kacc += 2*kv;  x0 = bf16(hb + alpha*kv + te)
// mode 2 (k4):   hn = h_f32 + dt6*(kacc + kv); h_out=hn; hb_out=bf16(hn);
//                if (x0_out) x0 = bf16(hn + te)
// ---------------------------------------------------------------------------
__global__ void __launch_bounds__(256, 2)
gemm_k(const bf16* __restrict__ A, const bf16* __restrict__ W,
       const float* __restrict__ bias, int K,
       bf16* __restrict__ kacc, const bf16* __restrict__ hb_src,
       const float* __restrict__ h_src, float* __restrict__ h_out,
       bf16* __restrict__ hb_out, bf16* __restrict__ x0_out,
       const float* __restrict__ temb, float alpha, float dt6, int mode) {
    constexpr int BM = 128, BN = 64, MT = 4, NT = 2;
    __shared__ alignas(16) bf16 lA[2][BM * 64];   // 2 x 16 KB
    __shared__ alignas(16) bf16 lB[2][BN * 64];   // 2 x  8 KB

    const int b   = blockIdx.x + gridDim.x * blockIdx.y;   // grid (8, 64)
    const int xcd = b & 7, j = b >> 3;
    const int bx  = j & 7;                                  // 8 N-tiles
    const int by  = xcd + 8 * (j >> 3);                     // 64 M-tiles

    const int tid  = threadIdx.x;
    const int lane = tid & 63;
    const int w    = tid >> 6;
    const int wr   = w >> 1, wc = w & 1;
    const int quad = lane >> 4, l16 = lane & 15;
    const int brow = by * BM;
    const int bcol = bx * BN;

    // staging: A = 128 rows x 8 chunks (1024 = 4/thread), B = 64 rows x 8
    // chunks (512 = 2/thread), 16 B each, XOR-8 swizzle.
    const bf16* gA[4]; int lqA[4];
    const bf16* gW[2]; int lqB[2];
#pragma unroll
    for (int jj = 0; jj < 4; ++jj) {
        const int q = tid + jj * 256;
        const int r = q >> 3, s = (q & 7) ^ (r & 7);
        gA[jj]  = A + (size_t)(brow + r) * K + s * 8;
        lqA[jj] = q * 8;
    }
#pragma unroll
    for (int jj = 0; jj < 2; ++jj) {
        const int q = tid + jj * 256;
        const int r = q >> 3, s = (q & 7) ^ (r & 7);
        gW[jj]  = W + (size_t)(bcol + r) * K + s * 8;
        lqB[jj] = q * 8;
    }

    floatx4 acc[MT][NT];
    const floatx4 zero = {0.f, 0.f, 0.f, 0.f};
#pragma unroll
    for (int mt = 0; mt < MT; ++mt)
#pragma unroll
        for (int nt = 0; nt < NT; ++nt) acc[mt][nt] = zero;

    const int arow0 = wr * 64 + l16;
    const int brow0 = wc * 32 + l16;
    const int x7 = l16 & 7;

    const int nIter = K / 64;   // 16 for K=1024
#pragma unroll
    for (int jj = 0; jj < 4; ++jj) load_lds16(gA[jj], &lA[0][0] + lqA[jj]);
#pragma unroll
    for (int jj = 0; jj < 2; ++jj) load_lds16(gW[jj], &lB[0][0] + lqB[jj]);

    for (int kt = 0; kt < nIter; ++kt) {
        const int cur = kt & 1;
        if (kt + 1 < nIter) {
#pragma unroll
            for (int jj = 0; jj < 4; ++jj)
                load_lds16(gA[jj] + (kt + 1) * 64, &lA[cur ^ 1][0] + lqA[jj]);
#pragma unroll
            for (int jj = 0; jj < 2; ++jj)
                load_lds16(gW[jj] + (kt + 1) * 64, &lB[cur ^ 1][0] + lqB[jj]);
            WAIT_VM(6);   // 6 prefetch loads in flight; previous tile drained
        } else {
            WAIT_VM(0);
        }
        __builtin_amdgcn_s_barrier();

#pragma unroll
        for (int kk = 0; kk < 2; ++kk) {
            const int sw = ((kk * 4 + quad) ^ x7) * 8;
            short8 af[MT], bfr[NT];
#pragma unroll
            for (int mt = 0; mt < MT; ++mt)
                af[mt] = *(const short8*)(&lA[cur][0] + (arow0 + mt * 16) * 64 + sw);
#pragma unroll
            for (int nt = 0; nt < NT; ++nt)
                bfr[nt] = *(const short8*)(&lB[cur][0] + (brow0 + nt * 16) * 64 + sw);
#pragma unroll
            for (int mt = 0; mt < MT; ++mt)
#pragma unroll
                for (int nt = 0; nt < NT; ++nt)
                    acc[mt][nt] = __builtin_amdgcn_mfma_f32_16x16x32_bf16(
                        af[mt], bfr[nt], acc[mt][nt], 0, 0, 0);
        }
        __builtin_amdgcn_s_barrier();
    }

    const int m0 = brow + wr * 64 + quad * 4;
    const int n0 = bcol + wc * 32 + l16;
#pragma unroll
    for (int mt = 0; mt < MT; ++mt)
#pragma unroll
        for (int nt = 0; nt < NT; ++nt) {
            const int n = n0 + nt * 16;
            const float bb = bias[n];
            const float te = temb[n];
#pragma unroll
            for (int i = 0; i < 4; ++i) {
                const int m = m0 + mt * 16 + i;
                const size_t idx = (size_t)m * 512 + n;
                const float kv = acc[mt][nt][i] + bb;
                if (mode == 0) {
                    kacc[idx] = __float2bfloat16(kv);
                    x0_out[idx] = __float2bfloat16(
                        __bfloat162float(hb_src[idx]) + alpha * kv + te);
                } else if (mode == 1) {
                    kacc[idx] = __float2bfloat16(__bfloat162float(kacc[idx]) + 2.f * kv);
                    x0_out[idx] = __float2bfloat16(
                        __bfloat162float(hb_src[idx]) + alpha * kv + te);
                } else {
                    const float hn = h_src[idx] + dt6 * (__bfloat162float(kacc[idx]) + kv);
                    h_out[idx] = hn;
                    hb_out[idx] = __float2bfloat16(hn);
                    if (x0_out) x0_out[idx] = __float2bfloat16(hn + te);
                }
            }
        }
}

__global__ void f2b_kern(const float* __restrict__ src, bf16* __restrict__ dst, int n) {
    const int i = blockIdx.x * blockDim.x + threadIdx.x;
    if (i < n) dst[i] = __float2bfloat16(src[i]);
}

// Per-row i8 quantization of W2 (N=1024 rows, K=1024): row n scaled by
// 127/rowmax_n (clamped), dq[n] = rowmax_n/127^2 (includes x1's /127).
__global__ void quantW2_row(const float* __restrict__ W, int K,
                            int8_t* __restrict__ out, float* __restrict__ dq) {
    __shared__ float red[256];
    const int row = blockIdx.x, tid = threadIdx.x;
    const float* src = W + (size_t)row * K;
    float m = 0.f;
    for (int k = tid; k < K; k += 256) m = fmaxf(m, fabsf(src[k]));
    red[tid] = m;
    __syncthreads();
    for (int s = 128; s > 0; s >>= 1) {
        if (tid < s) red[tid] = fmaxf(red[tid], red[tid + s]);
        __syncthreads();
    }
    const float rmax = fmaxf(red[0], 1e-8f);
    const float sc = 127.f / rmax;
    int8_t* dst = out + (size_t)row * K;
    for (int k = tid; k < K; k += 256) {
        int v = __float2int_rn(src[k] * sc);
        v = v > 127 ? 127 : (v < -127 ? -127 : v);
        dst[k] = (int8_t)v;
    }
    if (tid == 0) dq[row] = rmax / (127.f * 127.f);
}

// temb[j][n] = (j*dt/2)*Wt[n] + bt[n], j = 0..20
__global__ void temb_kern(const float* __restrict__ Wt, const float* __restrict__ bt,
                          float* __restrict__ temb, float half_dt, int total) {
    const int i = blockIdx.x * blockDim.x + threadIdx.x;
    if (i < total) {
        const int j = i >> 9, n = i & 511;
        temb[i] = (j * half_dt) * Wt[n] + bt[n];
    }
}

__global__ void prep_kern(const float* __restrict__ h, const float* __restrict__ temb0,
                          bf16* __restrict__ x0, bf16* __restrict__ hb, int total) {
    const int i = blockIdx.x * blockDim.x + threadIdx.x;
    if (i < total) {
        const float hv = h[i];
        x0[i] = __float2bfloat16(hv + temb0[i & 511]);
        hb[i] = __float2bfloat16(hv);
    }
}

extern "C" void kernel_launch(void* const* d_in, const int* in_sizes, int n_in,
                              void* d_out, int out_size, void* d_ws, size_t ws_size,
                              hipStream_t stream) {
    const float* h_in = (const float*)d_in[0];
    const float* W1 = (const float*)d_in[1];
    const float* b1 = (const float*)d_in[2];
    const float* W2 = (const float*)d_in[3];
    const float* b2 = (const float*)d_in[4];
    const float* W3 = (const float*)d_in[5];
    const float* b3 = (const float*)d_in[6];
    const float* Wt = (const float*)d_in[7];
    const float* bt = (const float*)d_in[8];
    // n_steps (d_in[9]) is a fixed Python scalar = 10.
    const int B = 8192, H = 512, H2 = 1024, NS = 10;
    const float dt = 1.f / NS;

    char* ws = (char*)d_ws;
    auto alloc = [&](size_t bytes) {
        char* p = ws;
        ws += (bytes + 255) & ~(size_t)255;
        return p;
    };
    bf16* W1b = (bf16*)alloc((size_t)H2 * H * 2);
    int8_t* W2i = (int8_t*)alloc((size_t)H2 * H2);      // i8, per-row scaled
    float* dq   = (float*)alloc((size_t)H2 * 4);        // per-row dequant
    bf16* W3b = (bf16*)alloc((size_t)H * H2 * 2);
    bf16* x0b = (bf16*)alloc((size_t)B * H * 2);
    int8_t* x1i = (int8_t*)alloc((size_t)B * H2);       // i8 tanh outputs *127
    bf16* x2b = (bf16*)alloc((size_t)B * H2 * 2);
    bf16* kacc = (bf16*)alloc((size_t)B * H * 2);
    bf16* hb   = (bf16*)alloc((size_t)B * H * 2);
    float* temb = (float*)alloc((size_t)21 * H * 4);
    float* hbuf = (float*)d_out;  // h ping-pongs through d_out (fp32)

    {
        int n = H2 * H;
        f2b_kern<<<(n + 255) / 256, 256, 0, stream>>>(W1, W1b, n);
        quantW2_row<<<H2, 256, 0, stream>>>(W2, H2, W2i, dq);
        n = H * H2;
        f2b_kern<<<(n + 255) / 256, 256, 0, stream>>>(W3, W3b, n);
    }
    {
        const int total = 21 * H;
        temb_kern<<<(total + 255) / 256, 256, 0, stream>>>(Wt, bt, temb, dt * 0.5f, total);
    }
    {
        const int total = B * H;
        prep_kern<<<(total + 255) / 256, 256, 0, stream>>>(h_in, temb, x0b, hb, total);
    }

    const dim3 blk256(256);
    const dim3 g12(H2 / 128, B / 128);  // 8 x 64 = 512 blocks (2/CU)
    const dim3 g3(H / 64, B / 128);     // 8 x 64 = 512 blocks (2/CU), 128x64 tile

    for (int s = 0; s < NS; ++s) {
        const float* hs = (s == 0) ? h_in : hbuf;
        const float* tmid = temb + (size_t)(2 * s + 1) * H;
        const float* tend = temb + (size_t)(2 * s + 2) * H;
        for (int e = 0; e < 4; ++e) {
            gemm_tanh4<<<g12, blk256, 0, stream>>>(x0b, W1b, b1, x1i, H, H2);
            gemm_tanh_i8<<<g12, blk256, 0, stream>>>(x1i, W2i, dq, b2, x2b, H2, H2);
            if (e == 0)
                gemm_k<<<g3, blk256, 0, stream>>>(x2b, W3b, b3, H2, kacc, hb, hs,
                                                  nullptr, nullptr, x0b, tmid,
                                                  dt * 0.5f, 0.f, 0);
            else if (e == 1)
                gemm_k<<<g3, blk256, 0, stream>>>(x2b, W3b, b3, H2, kacc, hb, hs,
                                                  nullptr, nullptr, x0b, tmid,
                                                  dt * 0.5f, 0.f, 1);
            else if (e == 2)
                gemm_k<<<g3, blk256, 0, stream>>>(x2b, W3b, b3, H2, kacc, hb, hs,
                                                  nullptr, nullptr, x0b, tend,
                                                  dt, 0.f, 1);
            else
                gemm_k<<<g3, blk256, 0, stream>>>(x2b, W3b, b3, H2, kacc, hb, hs,
                                                  hbuf, hb,
                                                  (s == NS - 1) ? nullptr : x0b,
                                                  tend, 0.f, dt / 6.f, 2);
        }
    }
}